// Round 4
// baseline (14697.429 us; speedup 1.0000x reference)
//
#include <hip/hip_runtime.h>

#define NTHR 256
#define B_TOT 262144
#define NCHUNK 1024            // B / 256 slot-chunks (cnt/bp entries)
#define NBLK2 512              // persistent grid (2 elements per thread)
#define NLEAF 16
#define BPL2 (NBLK2 / NLEAF)   // 32 blocks per leaf

typedef unsigned long long u64;

// ---------------------------------------------------------------------------
// shared helpers (used by BOTH persistent and fallback paths -> identical FP)
// ---------------------------------------------------------------------------

// index of the (n+1)-th set bit of m (n 0-based), 6-step binary search
__device__ __forceinline__ int nth_set_bit(u64 m, unsigned n) {
    int pos = 0;
#pragma unroll
    for (int st = 32; st; st >>= 1) {
        u64 low = (1ull << (pos + st)) - 1ull;
        if ((unsigned)__popcll(m & low) <= n) pos += st;
    }
    return pos;
}

// MLP + hysteresis update, arithmetic order identical to validated rounds 1-2
__device__ __forceinline__ void mlp_update(
    const float lin, const float x, const float isOn,
    const float* __restrict__ W1, const float* __restrict__ b1,
    const float* __restrict__ W2, const float* __restrict__ b2,
    const float* __restrict__ W3, const float* __restrict__ b3,
    float& x_new, float& isOn_new, bool& off)
{
    off = (isOn <= 0.5f);
    float h1[32];
#pragma unroll
    for (int j = 0; j < 32; ++j) {
        float a = lin * W1[j];
        a = fmaf(x, W1[32 + j], a);
        a += b1[j];
        h1[j] = fmaxf(a, 0.0f);
    }
    float o = 0.0f;
#pragma unroll
    for (int j = 0; j < 32; ++j) {
        float a = 0.0f;
#pragma unroll
        for (int k = 0; k < 32; ++k)
            a = fmaf(h1[k], W2[k * 32 + j], a);
        a += b2[j];
        a = fmaxf(a, 0.0f);
        o = fmaf(a, W3[j], o);
    }
    o += b3[0];
    const float plant = o * 10.0f;
    const float tm = x - plant;
    x_new = off ? tm : tm + 10.0f;
    isOn_new = off ? ((x_new <= 66.0f) ? 1.0f : isOn)
                   : ((x_new > 78.0f) ? 0.0f : isOn);
}

// source slot for destination slot i, given bp[] (excl off-prefix per chunk,
// in LDS), total off count T, and per-wave off masks mskP
__device__ __forceinline__ int resolve_src(const unsigned* bp,
                                           const u64* __restrict__ mskP,
                                           unsigned T, unsigned i)
{
    if (i < T) {
        const unsigned r = i;
        int b = 0;
#pragma unroll
        for (int st = NCHUNK / 2; st; st >>= 1) {
            const int nb = b + st;
            if (nb < NCHUNK && bp[nb] <= r) b = nb;
        }
        unsigned rr = r - bp[b];
        const u64 m0 = mskP[4 * b],     m1 = mskP[4 * b + 1];
        const u64 m2 = mskP[4 * b + 2], m3 = mskP[4 * b + 3];
        const unsigned p0 = __popcll(m0), p1 = __popcll(m1), p2 = __popcll(m2);
        int w; u64 m; unsigned nn;
        if (rr < p0)                { w = 0; m = m0; nn = rr; }
        else if (rr < p0 + p1)      { w = 1; m = m1; nn = rr - p0; }
        else if (rr < p0 + p1 + p2) { w = 2; m = m2; nn = rr - p0 - p1; }
        else                        { w = 3; m = m3; nn = rr - p0 - p1 - p2; }
        return b * NTHR + w * 64 + nth_set_bit(m, nn);
    } else {
        const unsigned q = i - T;
        int b = 0;
#pragma unroll
        for (int st = NCHUNK / 2; st; st >>= 1) {
            const int nb = b + st;
            if (nb < NCHUNK && ((unsigned)NTHR * (unsigned)nb - bp[nb]) <= q) b = nb;
        }
        unsigned qq = q - ((unsigned)NTHR * (unsigned)b - bp[b]);
        const u64 m0 = ~mskP[4 * b],     m1 = ~mskP[4 * b + 1];
        const u64 m2 = ~mskP[4 * b + 2], m3 = ~mskP[4 * b + 3];
        const unsigned p0 = __popcll(m0), p1 = __popcll(m1), p2 = __popcll(m2);
        int w; u64 m; unsigned nn;
        if (qq < p0)                { w = 0; m = m0; nn = qq; }
        else if (qq < p0 + p1)      { w = 1; m = m1; nn = qq - p0; }
        else if (qq < p0 + p1 + p2) { w = 2; m = m2; nn = qq - p0 - p1; }
        else                        { w = 3; m = m3; nn = qq - p0 - p1 - p2; }
        return b * NTHR + w * 64 + nth_set_bit(m, nn);
    }
}

// ---------------------------------------------------------------------------
// Persistent cooperative kernel: 512 blocks x 256 thr, 2 elements per thread
// (slots i0 and i0 + B/2). One tree grid-barrier per step.
// ---------------------------------------------------------------------------
__global__ __launch_bounds__(NTHR, 4) void persist2(
    const float2* __restrict__ inp,
    const float* __restrict__ W1, const float* __restrict__ b1,
    const float* __restrict__ W2, const float* __restrict__ b2,
    const float* __restrict__ W3, const float* __restrict__ b3,
    float2* __restrict__ st0, float2* __restrict__ st1,
    unsigned* __restrict__ cnt0, unsigned* __restrict__ cnt1,
    u64* __restrict__ msk0, u64* __restrict__ msk1,
    float* __restrict__ out,
    unsigned* __restrict__ bar,
    int nsteps)
{
    const int tid  = threadIdx.x;
    const int lane = tid & 63;
    const int wv   = tid >> 6;
    const int i0   = blockIdx.x * NTHR + tid;
    const int i1   = i0 + (B_TOT / 2);

    __shared__ unsigned bp[NCHUNK];
    __shared__ unsigned wsum[NTHR / 64];
    __shared__ unsigned wOff0[NTHR / 64], wOff1[NTHR / 64];

    float2* const stB[2]    = { st0, st1 };
    unsigned* const cntB[2] = { cnt0, cnt1 };
    u64* const mskB[2]      = { msk0, msk1 };

    const float lin0 = inp[i0].x;
    const float lin1 = inp[i1].x;
    float x0, on0, x1, on1;

    // build bp[] (exclusive off-prefix per chunk) + return total T
    auto scan_counts = [&](const unsigned* __restrict__ cntP) -> unsigned {
        const uint4 cc = ((const uint4*)cntP)[tid];
        const unsigned s = cc.x + cc.y + cc.z + cc.w;
        unsigned inc = s;
#pragma unroll
        for (int d = 1; d < 64; d <<= 1) {
            unsigned v = __shfl_up(inc, d);
            if (lane >= d) inc += v;
        }
        if (lane == 63) wsum[wv] = inc;
        __syncthreads();
        unsigned T = 0, wexcl = 0;
#pragma unroll
        for (int w = 0; w < NTHR / 64; ++w) {
            T += wsum[w];
            if (w < wv) wexcl += wsum[w];
        }
        unsigned r0 = wexcl + inc - s;
        const unsigned base = tid * 4;
        bp[base]     = r0; r0 += cc.x;
        bp[base + 1] = r0; r0 += cc.y;
        bp[base + 2] = r0; r0 += cc.z;
        bp[base + 3] = r0;
        __syncthreads();
        return T;
    };

    for (int t = 0; t < nsteps; ++t) {
        const int p = t & 1;
        if (t == 0) {
            x0 = inp[i0].y; on0 = 0.0f;
            x1 = inp[i1].y; on1 = 0.0f;
        } else {
            const unsigned T = scan_counts(cntB[p ^ 1]);
            const u64* mskP = mskB[p ^ 1];
            const float2* stP = stB[p ^ 1];
            const int s0 = resolve_src(bp, mskP, T, (unsigned)i0);
            const int s1 = resolve_src(bp, mskP, T, (unsigned)i1);
            const float2 v0 = stP[s0];
            const float2 v1 = stP[s1];
            x0 = v0.x; on0 = v0.y;
            x1 = v1.x; on1 = v1.y;
            out[(size_t)(t - 1) * B_TOT + i0] = x0;
            out[(size_t)(t - 1) * B_TOT + i1] = x1;
        }

        float xn0, onn0, xn1, onn1;
        bool off0, off1;
        mlp_update(lin0, x0, on0, W1, b1, W2, b2, W3, b3, xn0, onn0, off0);
        mlp_update(lin1, x1, on1, W1, b1, W2, b2, W3, b3, xn1, onn1, off1);

        stB[p][i0] = make_float2(xn0, onn0);
        stB[p][i1] = make_float2(xn1, onn1);

        const u64 m0 = __ballot(off0);
        const u64 m1 = __ballot(off1);
        if (lane == 0) {
            mskB[p][i0 >> 6] = m0;
            mskB[p][i1 >> 6] = m1;
            wOff0[wv] = (unsigned)__popcll(m0);
            wOff1[wv] = (unsigned)__popcll(m1);
        }
        __syncthreads();
        if (tid == 0) {
            unsigned sa = 0, sb = 0;
#pragma unroll
            for (int w = 0; w < NTHR / 64; ++w) { sa += wOff0[w]; sb += wOff1[w]; }
            cntB[p][blockIdx.x] = sa;
            cntB[p][blockIdx.x + NBLK2] = sb;
        }

        // ---- grid barrier (tree: 16 leaves x 32 blocks -> root) ----
        __syncthreads();
        if (tid == 0) {
            __threadfence();
            const int g = blockIdx.x & (NLEAF - 1);
            unsigned old = __hip_atomic_fetch_add(&bar[g * 16], 1u,
                               __ATOMIC_ACQ_REL, __HIP_MEMORY_SCOPE_AGENT);
            if (old == (unsigned)(t + 1) * BPL2 - 1u)
                __hip_atomic_fetch_add(&bar[NLEAF * 16], 1u,
                               __ATOMIC_ACQ_REL, __HIP_MEMORY_SCOPE_AGENT);
            const unsigned tgt = (unsigned)(t + 1) * NLEAF;
            while (__hip_atomic_load(&bar[NLEAF * 16],
                       __ATOMIC_ACQUIRE, __HIP_MEMORY_SCOPE_AGENT) < tgt)
                __builtin_amdgcn_s_sleep(2);
            __threadfence();
        }
        __syncthreads();
    }

    // final pull: traj row nsteps-1
    {
        const int p = (nsteps - 1) & 1;
        const unsigned T = scan_counts(cntB[p]);
        const int s0 = resolve_src(bp, mskB[p], T, (unsigned)i0);
        const int s1 = resolve_src(bp, mskB[p], T, (unsigned)i1);
        out[(size_t)(nsteps - 1) * B_TOT + i0] = stB[p][s0].x;
        out[(size_t)(nsteps - 1) * B_TOT + i1] = stB[p][s1].x;
    }
}

// ---------------------------------------------------------------------------
// Fallback: round-2 verified pull-fused chain (one kernel per step)
// ---------------------------------------------------------------------------
__global__ __launch_bounds__(NTHR) void fused_kernel(
    const float2* __restrict__ inp,
    const float* __restrict__ W1, const float* __restrict__ b1,
    const float* __restrict__ W2, const float* __restrict__ b2,
    const float* __restrict__ W3, const float* __restrict__ b3,
    const float2* __restrict__ stPrev, const unsigned* __restrict__ cntPrev,
    const u64* __restrict__ mskPrev,
    float2* __restrict__ stNew, unsigned* __restrict__ cntNew,
    u64* __restrict__ mskNew,
    float* __restrict__ outRow,
    int mode)
{
    const int tid  = threadIdx.x;
    const int lane = tid & 63;
    const int wv   = tid >> 6;
    const int i    = blockIdx.x * NTHR + tid;

    float x, isOn;
    if (mode == 0) {
        const float2 iv = inp[i];
        x = iv.y; isOn = 0.0f;
    } else {
        __shared__ unsigned bp[NCHUNK];
        __shared__ unsigned wsum[NTHR / 64];
        const uint4 cc = ((const uint4*)cntPrev)[tid];
        const unsigned s = cc.x + cc.y + cc.z + cc.w;
        unsigned inc = s;
#pragma unroll
        for (int d = 1; d < 64; d <<= 1) {
            unsigned v = __shfl_up(inc, d);
            if (lane >= d) inc += v;
        }
        if (lane == 63) wsum[wv] = inc;
        __syncthreads();
        unsigned T = 0, wexcl = 0;
#pragma unroll
        for (int w = 0; w < NTHR / 64; ++w) {
            T += wsum[w];
            if (w < wv) wexcl += wsum[w];
        }
        unsigned r0 = wexcl + inc - s;
        const unsigned base = tid * 4;
        bp[base]     = r0; r0 += cc.x;
        bp[base + 1] = r0; r0 += cc.y;
        bp[base + 2] = r0; r0 += cc.z;
        bp[base + 3] = r0;
        __syncthreads();

        const int src = resolve_src(bp, mskPrev, T, (unsigned)i);
        const float2 sv = stPrev[src];
        x = sv.x; isOn = sv.y;
        outRow[i] = x;
        if (mode == 2) return;
    }

    const float lin = inp[i].x;
    float x_new, isOn_new;
    bool off;
    mlp_update(lin, x, isOn, W1, b1, W2, b2, W3, b3, x_new, isOn_new, off);

    stNew[i] = make_float2(x_new, isOn_new);

    const u64 m = __ballot(off);
    __shared__ unsigned wOff[NTHR / 64];
    if (lane == 0) { mskNew[i >> 6] = m; wOff[wv] = (unsigned)__popcll(m); }
    __syncthreads();
    if (tid == 0) {
        unsigned ssum = 0;
#pragma unroll
        for (int w = 0; w < NTHR / 64; ++w) ssum += wOff[w];
        cntNew[blockIdx.x] = ssum;
    }
}

// ---------------------------------------------------------------------------
extern "C" void kernel_launch(void* const* d_in, const int* in_sizes, int n_in,
                              void* d_out, int out_size, void* d_ws, size_t ws_size,
                              hipStream_t stream)
{
    const float2* inp = (const float2*)d_in[0];
    const float* W1 = (const float*)d_in[1];
    const float* b1 = (const float*)d_in[2];
    const float* W2 = (const float*)d_in[3];
    const float* b2 = (const float*)d_in[4];
    const float* W3 = (const float*)d_in[5];
    const float* b3 = (const float*)d_in[6];
    float* out = (float*)d_out;

    const int B = in_sizes[0] / 2;          // 262144
    int nsteps = out_size / B;              // 40

    unsigned* bar = (unsigned*)d_ws;                     // 4 KiB barrier area
    float2*   st0 = (float2*)((char*)d_ws + 4096);
    float2*   st1 = st0 + B;
    unsigned* cnt0 = (unsigned*)(st1 + B);
    unsigned* cnt1 = cnt0 + NCHUNK;
    u64*      msk0 = (u64*)(cnt1 + NCHUNK);
    u64*      msk1 = msk0 + (B / 64);

    bool done = false;
    if (B == B_TOT) {
        hipMemsetAsync(bar, 0, 4096, stream);
        void* args[] = { (void*)&inp, (void*)&W1, (void*)&b1, (void*)&W2,
                         (void*)&b2, (void*)&W3, (void*)&b3,
                         (void*)&st0, (void*)&st1, (void*)&cnt0, (void*)&cnt1,
                         (void*)&msk0, (void*)&msk1, (void*)&out, (void*)&bar,
                         (void*)&nsteps };
        hipError_t e = hipLaunchCooperativeKernel((const void*)persist2,
                           dim3(NBLK2), dim3(NTHR), args, 0, stream);
        done = (e == hipSuccess);
    }

    if (!done) {
        // verified round-2 chain
        const int nblk = B / NTHR;
        fused_kernel<<<nblk, NTHR, 0, stream>>>(inp, W1, b1, W2, b2, W3, b3,
                                                st0, cnt0, msk0,
                                                st0, cnt0, msk0, nullptr, 0);
        for (int t = 1; t < nsteps; ++t) {
            const bool odd = (t & 1);
            const float2*   stP  = odd ? st0  : st1;
            const unsigned* cntP = odd ? cnt0 : cnt1;
            const u64*      mskP = odd ? msk0 : msk1;
            float2*   stN  = odd ? st1  : st0;
            unsigned* cntN = odd ? cnt1 : cnt0;
            u64*      mskN = odd ? msk1 : msk0;
            fused_kernel<<<nblk, NTHR, 0, stream>>>(inp, W1, b1, W2, b2, W3, b3,
                                                    stP, cntP, mskP,
                                                    stN, cntN, mskN,
                                                    out + (size_t)(t - 1) * B, 1);
        }
        const bool odd = (nsteps & 1);
        const float2*   stP  = odd ? st0  : st1;
        const unsigned* cntP = odd ? cnt0 : cnt1;
        const u64*      mskP = odd ? msk0 : msk1;
        fused_kernel<<<nblk, NTHR, 0, stream>>>(inp, W1, b1, W2, b2, W3, b3,
                                                stP, cntP, mskP,
                                                st0, cnt0, msk0,
                                                out + (size_t)(nsteps - 1) * B, 2);
    }
}

// Round 5
// 13780.801 us; speedup vs baseline: 1.0665x; 1.0665x over previous
//
#include <hip/hip_runtime.h>

#define NTHR 256
#define B_TOT 262144
#define NCHUNK 1024            // B / 256 slot-chunks (cnt/bp entries)
#define NBLK2 512              // persistent grid (2 elements per thread)
#define NLEAF 16
#define BPL2 (NBLK2 / NLEAF)   // 32 blocks per leaf

typedef unsigned long long u64;

// ---------------------------------------------------------------------------
// shared helpers (used by BOTH persistent and fallback paths -> identical FP)
// ---------------------------------------------------------------------------

// index of the (n+1)-th set bit of m (n 0-based), 6-step binary search
__device__ __forceinline__ int nth_set_bit(u64 m, unsigned n) {
    int pos = 0;
#pragma unroll
    for (int st = 32; st; st >>= 1) {
        u64 low = (1ull << (pos + st)) - 1ull;
        if ((unsigned)__popcll(m & low) <= n) pos += st;
    }
    return pos;
}

// MLP + hysteresis update, arithmetic order identical to validated rounds 1-2
__device__ __forceinline__ void mlp_update(
    const float lin, const float x, const float isOn,
    const float* __restrict__ W1, const float* __restrict__ b1,
    const float* __restrict__ W2, const float* __restrict__ b2,
    const float* __restrict__ W3, const float* __restrict__ b3,
    float& x_new, float& isOn_new, bool& off)
{
    off = (isOn <= 0.5f);
    float h1[32];
#pragma unroll
    for (int j = 0; j < 32; ++j) {
        float a = lin * W1[j];
        a = fmaf(x, W1[32 + j], a);
        a += b1[j];
        h1[j] = fmaxf(a, 0.0f);
    }
    float o = 0.0f;
#pragma unroll
    for (int j = 0; j < 32; ++j) {
        float a = 0.0f;
#pragma unroll
        for (int k = 0; k < 32; ++k)
            a = fmaf(h1[k], W2[k * 32 + j], a);
        a += b2[j];
        a = fmaxf(a, 0.0f);
        o = fmaf(a, W3[j], o);
    }
    o += b3[0];
    const float plant = o * 10.0f;
    const float tm = x - plant;
    x_new = off ? tm : tm + 10.0f;
    isOn_new = off ? ((x_new <= 66.0f) ? 1.0f : isOn)
                   : ((x_new > 78.0f) ? 0.0f : isOn);
}

// source slot for destination slot i, given bp[] (excl off-prefix per chunk,
// in LDS), total off count T, and per-wave off masks mskP
__device__ __forceinline__ int resolve_src(const unsigned* bp,
                                           const u64* __restrict__ mskP,
                                           unsigned T, unsigned i)
{
    if (i < T) {
        const unsigned r = i;
        int b = 0;
#pragma unroll
        for (int st = NCHUNK / 2; st; st >>= 1) {
            const int nb = b + st;
            if (nb < NCHUNK && bp[nb] <= r) b = nb;
        }
        unsigned rr = r - bp[b];
        const u64 m0 = mskP[4 * b],     m1 = mskP[4 * b + 1];
        const u64 m2 = mskP[4 * b + 2], m3 = mskP[4 * b + 3];
        const unsigned p0 = __popcll(m0), p1 = __popcll(m1), p2 = __popcll(m2);
        int w; u64 m; unsigned nn;
        if (rr < p0)                { w = 0; m = m0; nn = rr; }
        else if (rr < p0 + p1)      { w = 1; m = m1; nn = rr - p0; }
        else if (rr < p0 + p1 + p2) { w = 2; m = m2; nn = rr - p0 - p1; }
        else                        { w = 3; m = m3; nn = rr - p0 - p1 - p2; }
        return b * NTHR + w * 64 + nth_set_bit(m, nn);
    } else {
        const unsigned q = i - T;
        int b = 0;
#pragma unroll
        for (int st = NCHUNK / 2; st; st >>= 1) {
            const int nb = b + st;
            if (nb < NCHUNK && ((unsigned)NTHR * (unsigned)nb - bp[nb]) <= q) b = nb;
        }
        unsigned qq = q - ((unsigned)NTHR * (unsigned)b - bp[b]);
        const u64 m0 = ~mskP[4 * b],     m1 = ~mskP[4 * b + 1];
        const u64 m2 = ~mskP[4 * b + 2], m3 = ~mskP[4 * b + 3];
        const unsigned p0 = __popcll(m0), p1 = __popcll(m1), p2 = __popcll(m2);
        int w; u64 m; unsigned nn;
        if (qq < p0)                { w = 0; m = m0; nn = qq; }
        else if (qq < p0 + p1)      { w = 1; m = m1; nn = qq - p0; }
        else if (qq < p0 + p1 + p2) { w = 2; m = m2; nn = qq - p0 - p1; }
        else                        { w = 3; m = m3; nn = qq - p0 - p1 - p2; }
        return b * NTHR + w * 64 + nth_set_bit(m, nn);
    }
}

// ---------------------------------------------------------------------------
// Persistent cooperative kernel: 512 blocks x 256 thr, 2 elements per thread
// (slots i0 and i0 + B/2). One tree grid-barrier per step.
// Barrier memory-ordering: leaf fetch_add ACQ_REL (release = one L2 wb),
// root fetch_add RELEASE, waiters spin RELAXED (no invalidate per poll!),
// then ONE agent acquire fence after exit.
// ---------------------------------------------------------------------------
__global__ __launch_bounds__(NTHR, 4) void persist2(
    const float2* __restrict__ inp,
    const float* __restrict__ W1, const float* __restrict__ b1,
    const float* __restrict__ W2, const float* __restrict__ b2,
    const float* __restrict__ W3, const float* __restrict__ b3,
    float2* __restrict__ st0, float2* __restrict__ st1,
    unsigned* __restrict__ cnt0, unsigned* __restrict__ cnt1,
    u64* __restrict__ msk0, u64* __restrict__ msk1,
    float* __restrict__ out,
    unsigned* __restrict__ bar,
    int nsteps)
{
    const int tid  = threadIdx.x;
    const int lane = tid & 63;
    const int wv   = tid >> 6;
    const int i0   = blockIdx.x * NTHR + tid;
    const int i1   = i0 + (B_TOT / 2);

    __shared__ unsigned bp[NCHUNK];
    __shared__ unsigned wsum[NTHR / 64];
    __shared__ unsigned wOff0[NTHR / 64], wOff1[NTHR / 64];

    float2* const stB[2]    = { st0, st1 };
    unsigned* const cntB[2] = { cnt0, cnt1 };
    u64* const mskB[2]      = { msk0, msk1 };

    const float lin0 = inp[i0].x;
    const float lin1 = inp[i1].x;
    float x0, on0, x1, on1;

    // build bp[] (exclusive off-prefix per chunk) + return total T
    auto scan_counts = [&](const unsigned* __restrict__ cntP) -> unsigned {
        const uint4 cc = ((const uint4*)cntP)[tid];
        const unsigned s = cc.x + cc.y + cc.z + cc.w;
        unsigned inc = s;
#pragma unroll
        for (int d = 1; d < 64; d <<= 1) {
            unsigned v = __shfl_up(inc, d);
            if (lane >= d) inc += v;
        }
        if (lane == 63) wsum[wv] = inc;
        __syncthreads();
        unsigned T = 0, wexcl = 0;
#pragma unroll
        for (int w = 0; w < NTHR / 64; ++w) {
            T += wsum[w];
            if (w < wv) wexcl += wsum[w];
        }
        unsigned r0 = wexcl + inc - s;
        const unsigned base = tid * 4;
        bp[base]     = r0; r0 += cc.x;
        bp[base + 1] = r0; r0 += cc.y;
        bp[base + 2] = r0; r0 += cc.z;
        bp[base + 3] = r0;
        __syncthreads();
        return T;
    };

    for (int t = 0; t < nsteps; ++t) {
        const int p = t & 1;
        if (t == 0) {
            x0 = inp[i0].y; on0 = 0.0f;
            x1 = inp[i1].y; on1 = 0.0f;
        } else {
            const unsigned T = scan_counts(cntB[p ^ 1]);
            const u64* mskP = mskB[p ^ 1];
            const float2* stP = stB[p ^ 1];
            const int s0 = resolve_src(bp, mskP, T, (unsigned)i0);
            const int s1 = resolve_src(bp, mskP, T, (unsigned)i1);
            const float2 v0 = stP[s0];
            const float2 v1 = stP[s1];
            x0 = v0.x; on0 = v0.y;
            x1 = v1.x; on1 = v1.y;
            out[(size_t)(t - 1) * B_TOT + i0] = x0;
            out[(size_t)(t - 1) * B_TOT + i1] = x1;
        }

        float xn0, onn0, xn1, onn1;
        bool off0, off1;
        mlp_update(lin0, x0, on0, W1, b1, W2, b2, W3, b3, xn0, onn0, off0);
        mlp_update(lin1, x1, on1, W1, b1, W2, b2, W3, b3, xn1, onn1, off1);

        stB[p][i0] = make_float2(xn0, onn0);
        stB[p][i1] = make_float2(xn1, onn1);

        const u64 m0 = __ballot(off0);
        const u64 m1 = __ballot(off1);
        if (lane == 0) {
            mskB[p][i0 >> 6] = m0;
            mskB[p][i1 >> 6] = m1;
            wOff0[wv] = (unsigned)__popcll(m0);
            wOff1[wv] = (unsigned)__popcll(m1);
        }
        __syncthreads();
        if (tid == 0) {
            unsigned sa = 0, sb = 0;
#pragma unroll
            for (int w = 0; w < NTHR / 64; ++w) { sa += wOff0[w]; sb += wOff1[w]; }
            cntB[p][blockIdx.x] = sa;
            cntB[p][blockIdx.x + NBLK2] = sb;
        }

        // ---- grid barrier (tree: 16 leaves x 32 blocks -> root) ----
        __syncthreads();
        if (tid == 0) {
            const int g = blockIdx.x & (NLEAF - 1);
            // release part of ACQ_REL writes back this block's stores (L2 wb)
            unsigned old = __hip_atomic_fetch_add(&bar[g * 16], 1u,
                               __ATOMIC_ACQ_REL, __HIP_MEMORY_SCOPE_AGENT);
            if (old == (unsigned)(t + 1) * BPL2 - 1u)
                __hip_atomic_fetch_add(&bar[NLEAF * 16], 1u,
                               __ATOMIC_RELEASE, __HIP_MEMORY_SCOPE_AGENT);
            const unsigned tgt = (unsigned)(t + 1) * NLEAF;
            // RELAXED spin: no per-poll cache invalidate
            while (__hip_atomic_load(&bar[NLEAF * 16],
                       __ATOMIC_RELAXED, __HIP_MEMORY_SCOPE_AGENT) < tgt)
                __builtin_amdgcn_s_sleep(8);
            // one acquire fence for the whole step's pulled data
            __builtin_amdgcn_fence(__ATOMIC_ACQUIRE, "agent");
        }
        __syncthreads();
    }

    // final pull: traj row nsteps-1
    {
        const int p = (nsteps - 1) & 1;
        const unsigned T = scan_counts(cntB[p]);
        const int s0 = resolve_src(bp, mskB[p], T, (unsigned)i0);
        const int s1 = resolve_src(bp, mskB[p], T, (unsigned)i1);
        out[(size_t)(nsteps - 1) * B_TOT + i0] = stB[p][s0].x;
        out[(size_t)(nsteps - 1) * B_TOT + i1] = stB[p][s1].x;
    }
}

// ---------------------------------------------------------------------------
// Fallback: round-2 verified pull-fused chain (one kernel per step)
// ---------------------------------------------------------------------------
__global__ __launch_bounds__(NTHR) void fused_kernel(
    const float2* __restrict__ inp,
    const float* __restrict__ W1, const float* __restrict__ b1,
    const float* __restrict__ W2, const float* __restrict__ b2,
    const float* __restrict__ W3, const float* __restrict__ b3,
    const float2* __restrict__ stPrev, const unsigned* __restrict__ cntPrev,
    const u64* __restrict__ mskPrev,
    float2* __restrict__ stNew, unsigned* __restrict__ cntNew,
    u64* __restrict__ mskNew,
    float* __restrict__ outRow,
    int mode)
{
    const int tid  = threadIdx.x;
    const int lane = tid & 63;
    const int wv   = tid >> 6;
    const int i    = blockIdx.x * NTHR + tid;

    float x, isOn;
    if (mode == 0) {
        const float2 iv = inp[i];
        x = iv.y; isOn = 0.0f;
    } else {
        __shared__ unsigned bp[NCHUNK];
        __shared__ unsigned wsum[NTHR / 64];
        const uint4 cc = ((const uint4*)cntPrev)[tid];
        const unsigned s = cc.x + cc.y + cc.z + cc.w;
        unsigned inc = s;
#pragma unroll
        for (int d = 1; d < 64; d <<= 1) {
            unsigned v = __shfl_up(inc, d);
            if (lane >= d) inc += v;
        }
        if (lane == 63) wsum[wv] = inc;
        __syncthreads();
        unsigned T = 0, wexcl = 0;
#pragma unroll
        for (int w = 0; w < NTHR / 64; ++w) {
            T += wsum[w];
            if (w < wv) wexcl += wsum[w];
        }
        unsigned r0 = wexcl + inc - s;
        const unsigned base = tid * 4;
        bp[base]     = r0; r0 += cc.x;
        bp[base + 1] = r0; r0 += cc.y;
        bp[base + 2] = r0; r0 += cc.z;
        bp[base + 3] = r0;
        __syncthreads();

        const int src = resolve_src(bp, mskPrev, T, (unsigned)i);
        const float2 sv = stPrev[src];
        x = sv.x; isOn = sv.y;
        outRow[i] = x;
        if (mode == 2) return;
    }

    const float lin = inp[i].x;
    float x_new, isOn_new;
    bool off;
    mlp_update(lin, x, isOn, W1, b1, W2, b2, W3, b3, x_new, isOn_new, off);

    stNew[i] = make_float2(x_new, isOn_new);

    const u64 m = __ballot(off);
    __shared__ unsigned wOff[NTHR / 64];
    if (lane == 0) { mskNew[i >> 6] = m; wOff[wv] = (unsigned)__popcll(m); }
    __syncthreads();
    if (tid == 0) {
        unsigned ssum = 0;
#pragma unroll
        for (int w = 0; w < NTHR / 64; ++w) ssum += wOff[w];
        cntNew[blockIdx.x] = ssum;
    }
}

// ---------------------------------------------------------------------------
extern "C" void kernel_launch(void* const* d_in, const int* in_sizes, int n_in,
                              void* d_out, int out_size, void* d_ws, size_t ws_size,
                              hipStream_t stream)
{
    const float2* inp = (const float2*)d_in[0];
    const float* W1 = (const float*)d_in[1];
    const float* b1 = (const float*)d_in[2];
    const float* W2 = (const float*)d_in[3];
    const float* b2 = (const float*)d_in[4];
    const float* W3 = (const float*)d_in[5];
    const float* b3 = (const float*)d_in[6];
    float* out = (float*)d_out;

    const int B = in_sizes[0] / 2;          // 262144
    int nsteps = out_size / B;              // 40

    unsigned* bar = (unsigned*)d_ws;                     // 4 KiB barrier area
    float2*   st0 = (float2*)((char*)d_ws + 4096);
    float2*   st1 = st0 + B;
    unsigned* cnt0 = (unsigned*)(st1 + B);
    unsigned* cnt1 = cnt0 + NCHUNK;
    u64*      msk0 = (u64*)(cnt1 + NCHUNK);
    u64*      msk1 = msk0 + (B / 64);

    bool done = false;
    if (B == B_TOT) {
        hipMemsetAsync(bar, 0, 4096, stream);
        void* args[] = { (void*)&inp, (void*)&W1, (void*)&b1, (void*)&W2,
                         (void*)&b2, (void*)&W3, (void*)&b3,
                         (void*)&st0, (void*)&st1, (void*)&cnt0, (void*)&cnt1,
                         (void*)&msk0, (void*)&msk1, (void*)&out, (void*)&bar,
                         (void*)&nsteps };
        hipError_t e = hipLaunchCooperativeKernel((const void*)persist2,
                           dim3(NBLK2), dim3(NTHR), args, 0, stream);
        done = (e == hipSuccess);
    }

    if (!done) {
        // verified round-2 chain
        const int nblk = B / NTHR;
        fused_kernel<<<nblk, NTHR, 0, stream>>>(inp, W1, b1, W2, b2, W3, b3,
                                                st0, cnt0, msk0,
                                                st0, cnt0, msk0, nullptr, 0);
        for (int t = 1; t < nsteps; ++t) {
            const bool odd = (t & 1);
            const float2*   stP  = odd ? st0  : st1;
            const unsigned* cntP = odd ? cnt0 : cnt1;
            const u64*      mskP = odd ? msk0 : msk1;
            float2*   stN  = odd ? st1  : st0;
            unsigned* cntN = odd ? cnt1 : cnt0;
            u64*      mskN = odd ? msk1 : msk0;
            fused_kernel<<<nblk, NTHR, 0, stream>>>(inp, W1, b1, W2, b2, W3, b3,
                                                    stP, cntP, mskP,
                                                    stN, cntN, mskN,
                                                    out + (size_t)(t - 1) * B, 1);
        }
        const bool odd = (nsteps & 1);
        const float2*   stP  = odd ? st0  : st1;
        const unsigned* cntP = odd ? cnt0 : cnt1;
        const u64*      mskP = odd ? msk0 : msk1;
        fused_kernel<<<nblk, NTHR, 0, stream>>>(inp, W1, b1, W2, b2, W3, b3,
                                                stP, cntP, mskP,
                                                st0, cnt0, msk0,
                                                out + (size_t)(nsteps - 1) * B, 2);
    }
}

// Round 6
// 13510.211 us; speedup vs baseline: 1.0879x; 1.0200x over previous
//
#include <hip/hip_runtime.h>

#define NTHR 256
#define B_TOT 262144
#define NCHUNK 1024            // B / 256 slot-chunks (cnt/bp entries)
#define NBLK2 512              // persistent grid (2 elements per thread)
#define NLEAF 16
#define BPL2 (NBLK2 / NLEAF)   // 32 blocks per leaf

typedef unsigned long long u64;

// ---------------------------------------------------------------------------
// agent-scope RELAXED atomics: bypass non-coherent L2 (reach coherence point)
// WITHOUT any wbl2/inv cache maintenance. These are the ONLY ops touching
// cross-block state in the persistent kernel.
// ---------------------------------------------------------------------------
__device__ __forceinline__ u64 aload64(const u64* p) {
    return __hip_atomic_load((u64*)p, __ATOMIC_RELAXED, __HIP_MEMORY_SCOPE_AGENT);
}
__device__ __forceinline__ unsigned aload32(const unsigned* p) {
    return __hip_atomic_load((unsigned*)p, __ATOMIC_RELAXED, __HIP_MEMORY_SCOPE_AGENT);
}
__device__ __forceinline__ void astore64(u64* p, u64 v) {
    __hip_atomic_store(p, v, __ATOMIC_RELAXED, __HIP_MEMORY_SCOPE_AGENT);
}
__device__ __forceinline__ void astore32(unsigned* p, unsigned v) {
    __hip_atomic_store(p, v, __ATOMIC_RELAXED, __HIP_MEMORY_SCOPE_AGENT);
}

union f2u { float2 f; u64 u; };

// index of the (n+1)-th set bit of m (n 0-based), 6-step binary search
__device__ __forceinline__ int nth_set_bit(u64 m, unsigned n) {
    int pos = 0;
#pragma unroll
    for (int st = 32; st; st >>= 1) {
        u64 low = (1ull << (pos + st)) - 1ull;
        if ((unsigned)__popcll(m & low) <= n) pos += st;
    }
    return pos;
}

// MLP + hysteresis update, arithmetic order identical to validated rounds 1-2
__device__ __forceinline__ void mlp_update(
    const float lin, const float x, const float isOn,
    const float* __restrict__ W1, const float* __restrict__ b1,
    const float* __restrict__ W2, const float* __restrict__ b2,
    const float* __restrict__ W3, const float* __restrict__ b3,
    float& x_new, float& isOn_new, bool& off)
{
    off = (isOn <= 0.5f);
    float h1[32];
#pragma unroll
    for (int j = 0; j < 32; ++j) {
        float a = lin * W1[j];
        a = fmaf(x, W1[32 + j], a);
        a += b1[j];
        h1[j] = fmaxf(a, 0.0f);
    }
    float o = 0.0f;
#pragma unroll
    for (int j = 0; j < 32; ++j) {
        float a = 0.0f;
#pragma unroll
        for (int k = 0; k < 32; ++k)
            a = fmaf(h1[k], W2[k * 32 + j], a);
        a += b2[j];
        a = fmaxf(a, 0.0f);
        o = fmaf(a, W3[j], o);
    }
    o += b3[0];
    const float plant = o * 10.0f;
    const float tm = x - plant;
    x_new = off ? tm : tm + 10.0f;
    isOn_new = off ? ((x_new <= 66.0f) ? 1.0f : isOn)
                   : ((x_new > 78.0f) ? 0.0f : isOn);
}

// ---- resolve_src, normal-load variant (fallback chain) ----
__device__ __forceinline__ int resolve_src(const unsigned* bp,
                                           const u64* __restrict__ mskP,
                                           unsigned T, unsigned i)
{
    if (i < T) {
        const unsigned r = i;
        int b = 0;
#pragma unroll
        for (int st = NCHUNK / 2; st; st >>= 1) {
            const int nb = b + st;
            if (nb < NCHUNK && bp[nb] <= r) b = nb;
        }
        unsigned rr = r - bp[b];
        const u64 m0 = mskP[4 * b],     m1 = mskP[4 * b + 1];
        const u64 m2 = mskP[4 * b + 2], m3 = mskP[4 * b + 3];
        const unsigned p0 = __popcll(m0), p1 = __popcll(m1), p2 = __popcll(m2);
        int w; u64 m; unsigned nn;
        if (rr < p0)                { w = 0; m = m0; nn = rr; }
        else if (rr < p0 + p1)      { w = 1; m = m1; nn = rr - p0; }
        else if (rr < p0 + p1 + p2) { w = 2; m = m2; nn = rr - p0 - p1; }
        else                        { w = 3; m = m3; nn = rr - p0 - p1 - p2; }
        return b * NTHR + w * 64 + nth_set_bit(m, nn);
    } else {
        const unsigned q = i - T;
        int b = 0;
#pragma unroll
        for (int st = NCHUNK / 2; st; st >>= 1) {
            const int nb = b + st;
            if (nb < NCHUNK && ((unsigned)NTHR * (unsigned)nb - bp[nb]) <= q) b = nb;
        }
        unsigned qq = q - ((unsigned)NTHR * (unsigned)b - bp[b]);
        const u64 m0 = ~mskP[4 * b],     m1 = ~mskP[4 * b + 1];
        const u64 m2 = ~mskP[4 * b + 2], m3 = ~mskP[4 * b + 3];
        const unsigned p0 = __popcll(m0), p1 = __popcll(m1), p2 = __popcll(m2);
        int w; u64 m; unsigned nn;
        if (qq < p0)                { w = 0; m = m0; nn = qq; }
        else if (qq < p0 + p1)      { w = 1; m = m1; nn = qq - p0; }
        else if (qq < p0 + p1 + p2) { w = 2; m = m2; nn = qq - p0 - p1; }
        else                        { w = 3; m = m3; nn = qq - p0 - p1 - p2; }
        return b * NTHR + w * 64 + nth_set_bit(m, nn);
    }
}

// ---- resolve_src, agent-atomic-load variant (persistent kernel) ----
__device__ __forceinline__ int resolve_src_at(const unsigned* bp,
                                              const u64* __restrict__ mskP,
                                              unsigned T, unsigned i)
{
    if (i < T) {
        const unsigned r = i;
        int b = 0;
#pragma unroll
        for (int st = NCHUNK / 2; st; st >>= 1) {
            const int nb = b + st;
            if (nb < NCHUNK && bp[nb] <= r) b = nb;
        }
        unsigned rr = r - bp[b];
        const u64 m0 = aload64(mskP + 4 * b),     m1 = aload64(mskP + 4 * b + 1);
        const u64 m2 = aload64(mskP + 4 * b + 2), m3 = aload64(mskP + 4 * b + 3);
        const unsigned p0 = __popcll(m0), p1 = __popcll(m1), p2 = __popcll(m2);
        int w; u64 m; unsigned nn;
        if (rr < p0)                { w = 0; m = m0; nn = rr; }
        else if (rr < p0 + p1)      { w = 1; m = m1; nn = rr - p0; }
        else if (rr < p0 + p1 + p2) { w = 2; m = m2; nn = rr - p0 - p1; }
        else                        { w = 3; m = m3; nn = rr - p0 - p1 - p2; }
        return b * NTHR + w * 64 + nth_set_bit(m, nn);
    } else {
        const unsigned q = i - T;
        int b = 0;
#pragma unroll
        for (int st = NCHUNK / 2; st; st >>= 1) {
            const int nb = b + st;
            if (nb < NCHUNK && ((unsigned)NTHR * (unsigned)nb - bp[nb]) <= q) b = nb;
        }
        unsigned qq = q - ((unsigned)NTHR * (unsigned)b - bp[b]);
        const u64 m0 = ~aload64(mskP + 4 * b),     m1 = ~aload64(mskP + 4 * b + 1);
        const u64 m2 = ~aload64(mskP + 4 * b + 2), m3 = ~aload64(mskP + 4 * b + 3);
        const unsigned p0 = __popcll(m0), p1 = __popcll(m1), p2 = __popcll(m2);
        int w; u64 m; unsigned nn;
        if (qq < p0)                { w = 0; m = m0; nn = qq; }
        else if (qq < p0 + p1)      { w = 1; m = m1; nn = qq - p0; }
        else if (qq < p0 + p1 + p2) { w = 2; m = m2; nn = qq - p0 - p1; }
        else                        { w = 3; m = m3; nn = qq - p0 - p1 - p2; }
        return b * NTHR + w * 64 + nth_set_bit(m, nn);
    }
}

// ---------------------------------------------------------------------------
// Persistent cooperative kernel. ALL cross-block state via agent-relaxed
// atomics (cache-bypassing, no maintenance ops). Barrier: relaxed tree
// counters only; producer ordering via the vmcnt(0) drain that __syncthreads
// implies; consumer ordering via in-order per-wave issue after the spin.
// ---------------------------------------------------------------------------
__global__ __launch_bounds__(NTHR, 4) void persist2(
    const float2* __restrict__ inp,
    const float* __restrict__ W1, const float* __restrict__ b1,
    const float* __restrict__ W2, const float* __restrict__ b2,
    const float* __restrict__ W3, const float* __restrict__ b3,
    float2* __restrict__ st0, float2* __restrict__ st1,
    unsigned* __restrict__ cnt0, unsigned* __restrict__ cnt1,
    u64* __restrict__ msk0, u64* __restrict__ msk1,
    float* __restrict__ out,
    unsigned* __restrict__ bar,
    int nsteps)
{
    const int tid  = threadIdx.x;
    const int lane = tid & 63;
    const int wv   = tid >> 6;
    const int i0   = blockIdx.x * NTHR + tid;
    const int i1   = i0 + (B_TOT / 2);

    __shared__ unsigned bp[NCHUNK];
    __shared__ unsigned wsum[NTHR / 64];
    __shared__ unsigned wOff0[NTHR / 64], wOff1[NTHR / 64];

    float2* const stB[2]    = { st0, st1 };
    unsigned* const cntB[2] = { cnt0, cnt1 };
    u64* const mskB[2]      = { msk0, msk1 };

    const float lin0 = inp[i0].x;
    const float lin1 = inp[i1].x;
    float x0, on0, x1, on1;

    // build bp[] (exclusive off-prefix per chunk) + return total T
    auto scan_counts = [&](const unsigned* __restrict__ cntP) -> unsigned {
        const unsigned base4 = tid * 4;
        uint4 cc;
        cc.x = aload32(cntP + base4);
        cc.y = aload32(cntP + base4 + 1);
        cc.z = aload32(cntP + base4 + 2);
        cc.w = aload32(cntP + base4 + 3);
        const unsigned s = cc.x + cc.y + cc.z + cc.w;
        unsigned inc = s;
#pragma unroll
        for (int d = 1; d < 64; d <<= 1) {
            unsigned v = __shfl_up(inc, d);
            if (lane >= d) inc += v;
        }
        if (lane == 63) wsum[wv] = inc;
        __syncthreads();
        unsigned T = 0, wexcl = 0;
#pragma unroll
        for (int w = 0; w < NTHR / 64; ++w) {
            T += wsum[w];
            if (w < wv) wexcl += wsum[w];
        }
        unsigned r0 = wexcl + inc - s;
        bp[base4]     = r0; r0 += cc.x;
        bp[base4 + 1] = r0; r0 += cc.y;
        bp[base4 + 2] = r0; r0 += cc.z;
        bp[base4 + 3] = r0;
        __syncthreads();
        return T;
    };

    for (int t = 0; t < nsteps; ++t) {
        const int p = t & 1;
        if (t == 0) {
            x0 = inp[i0].y; on0 = 0.0f;
            x1 = inp[i1].y; on1 = 0.0f;
        } else {
            const unsigned T = scan_counts(cntB[p ^ 1]);
            const u64* mskP = mskB[p ^ 1];
            const u64* stP = (const u64*)stB[p ^ 1];
            const int s0 = resolve_src_at(bp, mskP, T, (unsigned)i0);
            const int s1 = resolve_src_at(bp, mskP, T, (unsigned)i1);
            f2u v0, v1;
            v0.u = aload64(stP + s0);
            v1.u = aload64(stP + s1);
            x0 = v0.f.x; on0 = v0.f.y;
            x1 = v1.f.x; on1 = v1.f.y;
            out[(size_t)(t - 1) * B_TOT + i0] = x0;   // host-read only: normal store
            out[(size_t)(t - 1) * B_TOT + i1] = x1;
        }

        float xn0, onn0, xn1, onn1;
        bool off0, off1;
        mlp_update(lin0, x0, on0, W1, b1, W2, b2, W3, b3, xn0, onn0, off0);
        mlp_update(lin1, x1, on1, W1, b1, W2, b2, W3, b3, xn1, onn1, off1);

        f2u w0, w1;
        w0.f = make_float2(xn0, onn0);
        w1.f = make_float2(xn1, onn1);
        astore64((u64*)stB[p] + i0, w0.u);
        astore64((u64*)stB[p] + i1, w1.u);

        const u64 m0 = __ballot(off0);
        const u64 m1 = __ballot(off1);
        if (lane == 0) {
            astore64(mskB[p] + (i0 >> 6), m0);
            astore64(mskB[p] + (i1 >> 6), m1);
            wOff0[wv] = (unsigned)__popcll(m0);
            wOff1[wv] = (unsigned)__popcll(m1);
        }
        __syncthreads();
        if (tid == 0) {
            unsigned sa = 0, sb = 0;
#pragma unroll
            for (int w = 0; w < NTHR / 64; ++w) { sa += wOff0[w]; sb += wOff1[w]; }
            astore32(cntB[p] + blockIdx.x, sa);
            astore32(cntB[p] + blockIdx.x + NBLK2, sb);
        }

        // ---- grid barrier: relaxed tree counters, ZERO cache maintenance ----
        __syncthreads();   // compiler drains vmcnt(0) per thread before s_barrier
        if (tid == 0) {
            asm volatile("s_waitcnt vmcnt(0)" ::: "memory");  // tid0's cnt stores
            const int g = blockIdx.x & (NLEAF - 1);
            unsigned old = __hip_atomic_fetch_add(&bar[g * 16], 1u,
                               __ATOMIC_RELAXED, __HIP_MEMORY_SCOPE_AGENT);
            if (old == (unsigned)(t + 1) * BPL2 - 1u)
                __hip_atomic_fetch_add(&bar[NLEAF * 16], 1u,
                               __ATOMIC_RELAXED, __HIP_MEMORY_SCOPE_AGENT);
            const unsigned tgt = (unsigned)(t + 1) * NLEAF;
            while (__hip_atomic_load(&bar[NLEAF * 16],
                       __ATOMIC_RELAXED, __HIP_MEMORY_SCOPE_AGENT) < tgt)
                __builtin_amdgcn_s_sleep(4);
            __atomic_signal_fence(__ATOMIC_SEQ_CST);  // compiler-only fence
        }
        __syncthreads();
    }

    // final pull: traj row nsteps-1
    {
        const int p = (nsteps - 1) & 1;
        const unsigned T = scan_counts(cntB[p]);
        const int s0 = resolve_src_at(bp, mskB[p], T, (unsigned)i0);
        const int s1 = resolve_src_at(bp, mskB[p], T, (unsigned)i1);
        f2u v0, v1;
        v0.u = aload64((const u64*)stB[p] + s0);
        v1.u = aload64((const u64*)stB[p] + s1);
        out[(size_t)(nsteps - 1) * B_TOT + i0] = v0.f.x;
        out[(size_t)(nsteps - 1) * B_TOT + i1] = v1.f.x;
    }
}

// ---------------------------------------------------------------------------
// Fallback: round-2 verified pull-fused chain (one kernel per step)
// ---------------------------------------------------------------------------
__global__ __launch_bounds__(NTHR) void fused_kernel(
    const float2* __restrict__ inp,
    const float* __restrict__ W1, const float* __restrict__ b1,
    const float* __restrict__ W2, const float* __restrict__ b2,
    const float* __restrict__ W3, const float* __restrict__ b3,
    const float2* __restrict__ stPrev, const unsigned* __restrict__ cntPrev,
    const u64* __restrict__ mskPrev,
    float2* __restrict__ stNew, unsigned* __restrict__ cntNew,
    u64* __restrict__ mskNew,
    float* __restrict__ outRow,
    int mode)
{
    const int tid  = threadIdx.x;
    const int lane = tid & 63;
    const int wv   = tid >> 6;
    const int i    = blockIdx.x * NTHR + tid;

    float x, isOn;
    if (mode == 0) {
        const float2 iv = inp[i];
        x = iv.y; isOn = 0.0f;
    } else {
        __shared__ unsigned bp[NCHUNK];
        __shared__ unsigned wsum[NTHR / 64];
        const uint4 cc = ((const uint4*)cntPrev)[tid];
        const unsigned s = cc.x + cc.y + cc.z + cc.w;
        unsigned inc = s;
#pragma unroll
        for (int d = 1; d < 64; d <<= 1) {
            unsigned v = __shfl_up(inc, d);
            if (lane >= d) inc += v;
        }
        if (lane == 63) wsum[wv] = inc;
        __syncthreads();
        unsigned T = 0, wexcl = 0;
#pragma unroll
        for (int w = 0; w < NTHR / 64; ++w) {
            T += wsum[w];
            if (w < wv) wexcl += wsum[w];
        }
        unsigned r0 = wexcl + inc - s;
        const unsigned base = tid * 4;
        bp[base]     = r0; r0 += cc.x;
        bp[base + 1] = r0; r0 += cc.y;
        bp[base + 2] = r0; r0 += cc.z;
        bp[base + 3] = r0;
        __syncthreads();

        const int src = resolve_src(bp, mskPrev, T, (unsigned)i);
        const float2 sv = stPrev[src];
        x = sv.x; isOn = sv.y;
        outRow[i] = x;
        if (mode == 2) return;
    }

    const float lin = inp[i].x;
    float x_new, isOn_new;
    bool off;
    mlp_update(lin, x, isOn, W1, b1, W2, b2, W3, b3, x_new, isOn_new, off);

    stNew[i] = make_float2(x_new, isOn_new);

    const u64 m = __ballot(off);
    __shared__ unsigned wOff[NTHR / 64];
    if (lane == 0) { mskNew[i >> 6] = m; wOff[wv] = (unsigned)__popcll(m); }
    __syncthreads();
    if (tid == 0) {
        unsigned ssum = 0;
#pragma unroll
        for (int w = 0; w < NTHR / 64; ++w) ssum += wOff[w];
        cntNew[blockIdx.x] = ssum;
    }
}

// ---------------------------------------------------------------------------
extern "C" void kernel_launch(void* const* d_in, const int* in_sizes, int n_in,
                              void* d_out, int out_size, void* d_ws, size_t ws_size,
                              hipStream_t stream)
{
    const float2* inp = (const float2*)d_in[0];
    const float* W1 = (const float*)d_in[1];
    const float* b1 = (const float*)d_in[2];
    const float* W2 = (const float*)d_in[3];
    const float* b2 = (const float*)d_in[4];
    const float* W3 = (const float*)d_in[5];
    const float* b3 = (const float*)d_in[6];
    float* out = (float*)d_out;

    const int B = in_sizes[0] / 2;          // 262144
    int nsteps = out_size / B;              // 40

    unsigned* bar = (unsigned*)d_ws;                     // 4 KiB barrier area
    float2*   st0 = (float2*)((char*)d_ws + 4096);
    float2*   st1 = st0 + B;
    unsigned* cnt0 = (unsigned*)(st1 + B);
    unsigned* cnt1 = cnt0 + NCHUNK;
    u64*      msk0 = (u64*)(cnt1 + NCHUNK);
    u64*      msk1 = msk0 + (B / 64);

    bool done = false;
    if (B == B_TOT) {
        hipMemsetAsync(bar, 0, 4096, stream);
        void* args[] = { (void*)&inp, (void*)&W1, (void*)&b1, (void*)&W2,
                         (void*)&b2, (void*)&W3, (void*)&b3,
                         (void*)&st0, (void*)&st1, (void*)&cnt0, (void*)&cnt1,
                         (void*)&msk0, (void*)&msk1, (void*)&out, (void*)&bar,
                         (void*)&nsteps };
        hipError_t e = hipLaunchCooperativeKernel((const void*)persist2,
                           dim3(NBLK2), dim3(NTHR), args, 0, stream);
        done = (e == hipSuccess);
    }

    if (!done) {
        // verified round-2 chain
        const int nblk = B / NTHR;
        fused_kernel<<<nblk, NTHR, 0, stream>>>(inp, W1, b1, W2, b2, W3, b3,
                                                st0, cnt0, msk0,
                                                st0, cnt0, msk0, nullptr, 0);
        for (int t = 1; t < nsteps; ++t) {
            const bool odd = (t & 1);
            const float2*   stP  = odd ? st0  : st1;
            const unsigned* cntP = odd ? cnt0 : cnt1;
            const u64*      mskP = odd ? msk0 : msk1;
            float2*   stN  = odd ? st1  : st0;
            unsigned* cntN = odd ? cnt1 : cnt0;
            u64*      mskN = odd ? msk1 : msk0;
            fused_kernel<<<nblk, NTHR, 0, stream>>>(inp, W1, b1, W2, b2, W3, b3,
                                                    stP, cntP, mskP,
                                                    stN, cntN, mskN,
                                                    out + (size_t)(t - 1) * B, 1);
        }
        const bool odd = (nsteps & 1);
        const float2*   stP  = odd ? st0  : st1;
        const unsigned* cntP = odd ? cnt0 : cnt1;
        const u64*      mskP = odd ? msk0 : msk1;
        fused_kernel<<<nblk, NTHR, 0, stream>>>(inp, W1, b1, W2, b2, W3, b3,
                                                stP, cntP, mskP,
                                                st0, cnt0, msk0,
                                                out + (size_t)(nsteps - 1) * B, 2);
    }
}

// Round 7
// 394.885 us; speedup vs baseline: 37.2195x; 34.2130x over previous
//
#include <hip/hip_runtime.h>

#define NTHR 256
#define NCHUNK 1024            // B / 256 slot-chunks (cnt/bp entries)

typedef unsigned long long u64;
typedef float v2 __attribute__((ext_vector_type(2)));

// ---------------------------------------------------------------------------
// index of the (n+1)-th set bit of m (n 0-based), 6-step binary search
__device__ __forceinline__ int nth_set_bit(u64 m, unsigned n) {
    int pos = 0;
#pragma unroll
    for (int st = 32; st; st >>= 1) {
        u64 low = (1ull << (pos + st)) - 1ull;
        if ((unsigned)__popcll(m & low) <= n) pos += st;
    }
    return pos;
}

// ---------------------------------------------------------------------------
// MLP + hysteresis. Packed-FP32 pairs over output neurons (j, j+1):
// per-ELEMENT arithmetic (k-sequential fma from 0, +bias, relu, j-sequential
// layer-3 accumulation) is byte-identical to the validated scalar version —
// v_pk_* ops round each 32-bit half exactly like the scalar op.
// ---------------------------------------------------------------------------
__device__ __forceinline__ void mlp_update(
    const float lin, const float x, const float isOn,
    const float* __restrict__ W1, const float* __restrict__ b1,
    const float* __restrict__ W2, const float* __restrict__ b2,
    const float* __restrict__ W3, const float* __restrict__ b3,
    float& x_new, float& isOn_new, bool& off)
{
    off = (isOn <= 0.5f);

    const v2* __restrict__ W1r0 = (const v2*)W1;          // row 0 (lin weights)
    const v2* __restrict__ W1r1 = (const v2*)(W1 + 32);   // row 1 (x weights)
    const v2* __restrict__ b1p  = (const v2*)b1;
    const v2* __restrict__ b2p  = (const v2*)b2;

    const v2 linv = { lin, lin };
    const v2 xv   = { x, x };

    // layer 1: 16 neuron-pairs; per element: mul, fma, add, relu (same order)
    v2 h1v[16];
#pragma unroll
    for (int jp = 0; jp < 16; ++jp) {
        v2 a = linv * W1r0[jp];                       // v_pk_mul_f32
        a = __builtin_elementwise_fma(xv, W1r1[jp], a); // v_pk_fma_f32
        a = a + b1p[jp];                              // v_pk_add_f32
        a.x = fmaxf(a.x, 0.0f);
        a.y = fmaxf(a.y, 0.0f);
        h1v[jp] = a;
    }
    // splat each h1[k] into both halves once (32 movs, reused 16x each)
    v2 h1s[32];
#pragma unroll
    for (int jp = 0; jp < 16; ++jp) {
        h1s[2 * jp]     = h1v[jp].xx;
        h1s[2 * jp + 1] = h1v[jp].yy;
    }

    // layer 2 + fused layer 3 (layer-3 accumulation stays scalar j-order)
    float o = 0.0f;
#pragma unroll
    for (int jp = 0; jp < 16; ++jp) {
        v2 a = { 0.0f, 0.0f };
        const v2* __restrict__ w2col = (const v2*)(W2) + jp;  // stride 16 v2/row
#pragma unroll
        for (int k = 0; k < 32; ++k)
            a = __builtin_elementwise_fma(h1s[k], w2col[k * 16], a);
        a = a + b2p[jp];
        const float ax = fmaxf(a.x, 0.0f);
        const float ay = fmaxf(a.y, 0.0f);
        o = fmaf(ax, W3[2 * jp], o);
        o = fmaf(ay, W3[2 * jp + 1], o);
    }
    o += b3[0];

    const float plant = o * 10.0f;
    const float tm = x - plant;
    x_new = off ? tm : tm + 10.0f;
    isOn_new = off ? ((x_new <= 66.0f) ? 1.0f : isOn)
                   : ((x_new > 78.0f) ? 0.0f : isOn);
}

// ---------------------------------------------------------------------------
// source slot for destination slot i, given bp[] (excl off-prefix per chunk,
// in LDS), total off count T, and per-wave off masks mskP
// ---------------------------------------------------------------------------
__device__ __forceinline__ int resolve_src(const unsigned* bp,
                                           const u64* __restrict__ mskP,
                                           unsigned T, unsigned i)
{
    if (i < T) {
        const unsigned r = i;
        int b = 0;
#pragma unroll
        for (int st = NCHUNK / 2; st; st >>= 1) {
            const int nb = b + st;
            if (nb < NCHUNK && bp[nb] <= r) b = nb;
        }
        unsigned rr = r - bp[b];
        const u64 m0 = mskP[4 * b],     m1 = mskP[4 * b + 1];
        const u64 m2 = mskP[4 * b + 2], m3 = mskP[4 * b + 3];
        const unsigned p0 = __popcll(m0), p1 = __popcll(m1), p2 = __popcll(m2);
        int w; u64 m; unsigned nn;
        if (rr < p0)                { w = 0; m = m0; nn = rr; }
        else if (rr < p0 + p1)      { w = 1; m = m1; nn = rr - p0; }
        else if (rr < p0 + p1 + p2) { w = 2; m = m2; nn = rr - p0 - p1; }
        else                        { w = 3; m = m3; nn = rr - p0 - p1 - p2; }
        return b * NTHR + w * 64 + nth_set_bit(m, nn);
    } else {
        const unsigned q = i - T;
        int b = 0;
#pragma unroll
        for (int st = NCHUNK / 2; st; st >>= 1) {
            const int nb = b + st;
            if (nb < NCHUNK && ((unsigned)NTHR * (unsigned)nb - bp[nb]) <= q) b = nb;
        }
        unsigned qq = q - ((unsigned)NTHR * (unsigned)b - bp[b]);
        const u64 m0 = ~mskP[4 * b],     m1 = ~mskP[4 * b + 1];
        const u64 m2 = ~mskP[4 * b + 2], m3 = ~mskP[4 * b + 3];
        const unsigned p0 = __popcll(m0), p1 = __popcll(m1), p2 = __popcll(m2);
        int w; u64 m; unsigned nn;
        if (qq < p0)                { w = 0; m = m0; nn = qq; }
        else if (qq < p0 + p1)      { w = 1; m = m1; nn = qq - p0; }
        else if (qq < p0 + p1 + p2) { w = 2; m = m2; nn = qq - p0 - p1; }
        else                        { w = 3; m = m3; nn = qq - p0 - p1 - p2; }
        return b * NTHR + w * 64 + nth_set_bit(m, nn);
    }
}

// ---------------------------------------------------------------------------
// One kernel per simulation step (verified round-2 structure).
//   mode 0: first step  — x from input, isOn=0, no pull
//   mode 1: middle step — pull permuted state, write traj row t-1, compute
//   mode 2: final pull  — pull only, write last traj row
// ---------------------------------------------------------------------------
__global__ __launch_bounds__(NTHR, 4) void fused_kernel(
    const float2* __restrict__ inp,
    const float* __restrict__ W1, const float* __restrict__ b1,
    const float* __restrict__ W2, const float* __restrict__ b2,
    const float* __restrict__ W3, const float* __restrict__ b3,
    const float2* __restrict__ stPrev, const unsigned* __restrict__ cntPrev,
    const u64* __restrict__ mskPrev,
    float2* __restrict__ stNew, unsigned* __restrict__ cntNew,
    u64* __restrict__ mskNew,
    float* __restrict__ outRow,
    int mode)
{
    const int tid  = threadIdx.x;
    const int lane = tid & 63;
    const int wv   = tid >> 6;
    const int i    = blockIdx.x * NTHR + tid;

    float x, isOn;
    if (mode == 0) {
        const float2 iv = inp[i];
        x = iv.y; isOn = 0.0f;
    } else {
        __shared__ unsigned bp[NCHUNK];
        __shared__ unsigned wsum[NTHR / 64];
        const uint4 cc = ((const uint4*)cntPrev)[tid];
        const unsigned s = cc.x + cc.y + cc.z + cc.w;
        unsigned inc = s;
#pragma unroll
        for (int d = 1; d < 64; d <<= 1) {
            unsigned v = __shfl_up(inc, d);
            if (lane >= d) inc += v;
        }
        if (lane == 63) wsum[wv] = inc;
        __syncthreads();
        unsigned T = 0, wexcl = 0;
#pragma unroll
        for (int w = 0; w < NTHR / 64; ++w) {
            T += wsum[w];
            if (w < wv) wexcl += wsum[w];
        }
        unsigned r0 = wexcl + inc - s;
        const unsigned base = tid * 4;
        bp[base]     = r0; r0 += cc.x;
        bp[base + 1] = r0; r0 += cc.y;
        bp[base + 2] = r0; r0 += cc.z;
        bp[base + 3] = r0;
        __syncthreads();

        const int src = resolve_src(bp, mskPrev, T, (unsigned)i);
        const float2 sv = stPrev[src];
        x = sv.x; isOn = sv.y;
        outRow[i] = x;
        if (mode == 2) return;
    }

    const float lin = inp[i].x;
    float x_new, isOn_new;
    bool off;
    mlp_update(lin, x, isOn, W1, b1, W2, b2, W3, b3, x_new, isOn_new, off);

    stNew[i] = make_float2(x_new, isOn_new);

    const u64 m = __ballot(off);
    __shared__ unsigned wOff[NTHR / 64];
    if (lane == 0) { mskNew[i >> 6] = m; wOff[wv] = (unsigned)__popcll(m); }
    __syncthreads();
    if (tid == 0) {
        unsigned ssum = 0;
#pragma unroll
        for (int w = 0; w < NTHR / 64; ++w) ssum += wOff[w];
        cntNew[blockIdx.x] = ssum;
    }
}

// ---------------------------------------------------------------------------
extern "C" void kernel_launch(void* const* d_in, const int* in_sizes, int n_in,
                              void* d_out, int out_size, void* d_ws, size_t ws_size,
                              hipStream_t stream)
{
    const float2* inp = (const float2*)d_in[0];
    const float* W1 = (const float*)d_in[1];
    const float* b1 = (const float*)d_in[2];
    const float* W2 = (const float*)d_in[3];
    const float* b2 = (const float*)d_in[4];
    const float* W3 = (const float*)d_in[5];
    const float* b3 = (const float*)d_in[6];
    float* out = (float*)d_out;

    const int B = in_sizes[0] / 2;          // 262144
    const int nsteps = out_size / B;        // 40
    const int nblk = B / NTHR;              // 1024

    float2*   st0 = (float2*)d_ws;
    float2*   st1 = st0 + B;
    unsigned* cnt0 = (unsigned*)(st1 + B);
    unsigned* cnt1 = cnt0 + NCHUNK;
    u64*      msk0 = (u64*)(cnt1 + NCHUNK);
    u64*      msk1 = msk0 + (B / 64);

    // step 0: no pull
    fused_kernel<<<nblk, NTHR, 0, stream>>>(inp, W1, b1, W2, b2, W3, b3,
                                            st0, cnt0, msk0,
                                            st0, cnt0, msk0, nullptr, 0);
    // steps 1..nsteps-1: pull prev (writes traj row t-1) + compute step t
    for (int t = 1; t < nsteps; ++t) {
        const bool odd = (t & 1);
        const float2*   stP  = odd ? st0  : st1;
        const unsigned* cntP = odd ? cnt0 : cnt1;
        const u64*      mskP = odd ? msk0 : msk1;
        float2*   stN  = odd ? st1  : st0;
        unsigned* cntN = odd ? cnt1 : cnt0;
        u64*      mskN = odd ? msk1 : msk0;
        fused_kernel<<<nblk, NTHR, 0, stream>>>(inp, W1, b1, W2, b2, W3, b3,
                                                stP, cntP, mskP,
                                                stN, cntN, mskN,
                                                out + (size_t)(t - 1) * B, 1);
    }
    // final pull-only: traj row nsteps-1
    {
        const bool odd = (nsteps & 1);
        const float2*   stP  = odd ? st0  : st1;
        const unsigned* cntP = odd ? cnt0 : cnt1;
        const u64*      mskP = odd ? msk0 : msk1;
        fused_kernel<<<nblk, NTHR, 0, stream>>>(inp, W1, b1, W2, b2, W3, b3,
                                                stP, cntP, mskP,
                                                st0, cnt0, msk0,
                                                out + (size_t)(nsteps - 1) * B, 2);
    }
}